// Round 4
// baseline (286.573 us; speedup 1.0000x reference)
//
#include <hip/hip_runtime.h>
#include <hip/hip_bf16.h>
#include <math.h>

// Problem constants
#define NB 65536
#define ND 256
#define NE 16
#define NH 64
#define NA 18

typedef __bf16 bf16;
typedef __bf16 bf16x4 __attribute__((ext_vector_type(4)));
typedef __bf16 bf16x8 __attribute__((ext_vector_type(8)));
typedef float  f32x4  __attribute__((ext_vector_type(4)));

// ---- workspace layout (bytes) ----
#define OFF_WCAT 0u
#define OFF_BCAT 1048576u
#define OFF_PW1  1052672u
#define OFF_B1   2101248u
#define OFF_CUR  2109440u
#define OFF_PERM 2109504u

__device__ __forceinline__ float rcp_(float x) { return __builtin_amdgcn_rcpf(x); }
__device__ __forceinline__ float sigm_(float x) {
    return rcp_(1.f + __expf(-x));
}
__device__ __forceinline__ float tanh_(float x) {
    float cl = fminf(fmaxf(x, -15.f), 15.f);
    float e = __expf(2.f * cl);
    return (e - 1.f) * rcp_(e + 1.f);
}

// ---------------- prep1: pack LSTM weights, fuse biases, init cursors ----------------
__global__ void k_prep1(const float* __restrict__ W_ih, const float* __restrict__ W_hh,
                        const float* __restrict__ b_ih, const float* __restrict__ b_hh,
                        char* __restrict__ ws) {
    int t = blockIdx.x * 256 + threadIdx.x;        // 65536 = 64 kc * 1024 col
    bf16* Wcat = (bf16*)(ws + OFF_WCAT);
    int kc = t & 63, col = t >> 6;
    int k = kc * 8;
    const float* src = (k < 256) ? (W_ih + (size_t)col * 256 + k)
                                 : (W_hh + (size_t)col * 256 + (k - 256));
    float4 v0 = *(const float4*)(src);
    float4 v1 = *(const float4*)(src + 4);
    bf16x8 o;
    o[0] = (bf16)v0.x; o[1] = (bf16)v0.y; o[2] = (bf16)v0.z; o[3] = (bf16)v0.w;
    o[4] = (bf16)v1.x; o[5] = (bf16)v1.y; o[6] = (bf16)v1.z; o[7] = (bf16)v1.w;
    *(bf16x8*)(Wcat + ((size_t)kc * 1024 + col) * 8) = o;
    if (t < 1024) ((float*)(ws + OFF_BCAT))[t] = b_ih[t] + b_hh[t];
    if (t < 16)   ((int*)(ws + OFF_CUR))[t] = t * 65536;   // bucket cursor init (every call)
}

// ---------------- prep2: pack expert layer-1 weights (actor|critic), fuse biases ----------------
__global__ void k_prep2(const float* __restrict__ Wa1, const float* __restrict__ Wc1,
                        const float* __restrict__ ba1, const float* __restrict__ bc1,
                        char* __restrict__ ws) {
    int t = blockIdx.x * 256 + threadIdx.x;        // 65536 = 16 e * 32 kc * 128 col
    bf16* PW1 = (bf16*)(ws + OFF_PW1);
    int col = t & 127, kc = (t >> 7) & 31, e = t >> 12;
    bf16x8 o;
#pragma unroll
    for (int j = 0; j < 8; ++j) {
        int k = kc * 8 + j;
        float v = (col < 64) ? Wa1[((size_t)e * 256 + k) * 64 + col]
                             : Wc1[((size_t)e * 256 + k) * 64 + (col - 64)];
        o[j] = (bf16)v;
    }
    *(bf16x8*)(PW1 + (((size_t)e * 32 + kc) * 128 + col) * 8) = o;
    if (t < 2048) {
        int e2 = t >> 7, c = t & 127;
        ((float*)(ws + OFF_B1))[t] = (c < 64) ? ba1[e2 * 64 + c] : bc1[e2 * 64 + (c - 64)];
    }
}

// ---------------- scatter: bucket rows by expert (order-free => deterministic outputs) ----------------
__global__ void k_scatter(const int* __restrict__ idxs, char* __restrict__ ws) {
    __shared__ int lh[16], lbase[16];
    int t = threadIdx.x;
    int i = blockIdx.x * 256 + t;
    if (t < 16) lh[t] = 0;
    __syncthreads();
    int e = idxs[i];
    int r = atomicAdd(&lh[e], 1);
    __syncthreads();
    int* cur = (int*)(ws + OFF_CUR);
    if (t < 16) lbase[t] = atomicAdd(&cur[t], lh[t]);
    __syncthreads();
    ((int*)(ws + OFF_PERM))[lbase[e] + r] = i;
}

// ---------------- k_lstm v4: whole-A-tile LDS + register B double-buffer ----------------
// 512 thr (8 waves), block = 64 rows x 256 c-cols (full width, x4 gates).
// Wave w owns c-cols [32w, 32w+32): acc[4 m][8 n] = 128 AGPR; launch_bounds(512,2)
// gives ~256 unified regs so B(kf+1) prefetch lives in registers across kf's MFMAs.
// LDS 64KB -> 2 blocks/CU. One barrier total.
__global__ __launch_bounds__(512, 2) void k_lstm(
    const float* __restrict__ obs, const float* __restrict__ hin,
    const float* __restrict__ cin, const float* __restrict__ bcat,
    const bf16* __restrict__ Wcat,
    float* __restrict__ hout, float* __restrict__ cout) {
    __shared__ alignas(16) char Alds[65536];   // [kc 0..63][64 rows][16B], swizzled
    const int tid  = threadIdx.x;
    const int wave = tid >> 6, lane = tid & 63;
    const int lr = lane & 15, lk = lane >> 4;
    const int row0 = blockIdx.x * 64;

    // ---- stage full A tile (64 rows x 512 k, fp32->bf16), coalesced ----
    {
        int sr = tid >> 3, j = tid & 7;
        const float* baseO = obs + (size_t)(row0 + sr) * 256;
        const float* baseH = hin + (size_t)(row0 + sr) * 256;
#pragma unroll
        for (int s = 0; s < 8; ++s) {
            int kc = s * 8 + j;                       // 0..63
            const float* sp = (s < 4) ? (baseO + kc * 8) : (baseH + (kc - 32) * 8);
            float4 v0 = *(const float4*)sp;
            float4 v1 = *(const float4*)(sp + 4);
            bf16x8 o;
            o[0] = (bf16)v0.x; o[1] = (bf16)v0.y; o[2] = (bf16)v0.z; o[3] = (bf16)v0.w;
            o[4] = (bf16)v1.x; o[5] = (bf16)v1.y; o[6] = (bf16)v1.z; o[7] = (bf16)v1.w;
            *(bf16x8*)(Alds + kc * 1024 + (((sr ^ (kc & 7))) * 16)) = o;
        }
    }
    __syncthreads();   // the ONLY barrier

    // A-frag LDS byte offsets; kc&7 = (kf&1)*4 + lk
    int offE[4], offO[4];
#pragma unroll
    for (int m = 0; m < 4; ++m) {
        int R = m * 16 + lr;
        offE[m] = lk * 1024 + ((R ^ lk) * 16);
        offO[m] = lk * 1024 + ((R ^ (lk + 4)) * 16);
    }

    f32x4 acc[4][8];   // [m][g*2+j]
#pragma unroll
    for (int m = 0; m < 4; ++m)
#pragma unroll
        for (int n = 0; n < 8; ++n)
#pragma unroll
            for (int r = 0; r < 4; ++r) acc[m][n][r] = 0.f;

    // B base: col(g,j) = g*256 + wave*32 + j*16 + lr ; elem off = (kc*1024+col)*8
    const bf16* pB = Wcat + ((size_t)lk * 1024 + wave * 32 + lr) * 8;
    // per-n elem offsets: n=g*2+j -> g*2048 + j*128 ; per-kf stride 32768 elems
#define BOFF(g, j) ((g) * 2048 + (j) * 128)

    bf16x8 B0[8], B1[8];
#define LOADB(dst, kf)                                                        \
    {                                                                         \
        const bf16* p_ = pB + (size_t)(kf) * 32768;                           \
        dst[0] = *(const bf16x8*)(p_ + BOFF(0, 0));                           \
        dst[1] = *(const bf16x8*)(p_ + BOFF(0, 1));                           \
        dst[2] = *(const bf16x8*)(p_ + BOFF(1, 0));                           \
        dst[3] = *(const bf16x8*)(p_ + BOFF(1, 1));                           \
        dst[4] = *(const bf16x8*)(p_ + BOFF(2, 0));                           \
        dst[5] = *(const bf16x8*)(p_ + BOFF(2, 1));                           \
        dst[6] = *(const bf16x8*)(p_ + BOFF(3, 0));                           \
        dst[7] = *(const bf16x8*)(p_ + BOFF(3, 1));                           \
    }

#define STEP(kf, BCUR, BNXT, OFFA)                                            \
    {                                                                         \
        if ((kf) < 15) LOADB(BNXT, (kf) + 1);                                 \
        const char* Ab_ = Alds + (kf) * 4096;                                 \
        bf16x8 a0 = *(const bf16x8*)(Ab_ + OFFA[0]);                          \
        bf16x8 a1 = *(const bf16x8*)(Ab_ + OFFA[1]);                          \
        bf16x8 a2 = *(const bf16x8*)(Ab_ + OFFA[2]);                          \
        bf16x8 a3 = *(const bf16x8*)(Ab_ + OFFA[3]);                          \
        _Pragma("unroll")                                                     \
        for (int n = 0; n < 8; ++n) {                                         \
            acc[0][n] = __builtin_amdgcn_mfma_f32_16x16x32_bf16(a0, BCUR[n], acc[0][n], 0, 0, 0); \
            acc[1][n] = __builtin_amdgcn_mfma_f32_16x16x32_bf16(a1, BCUR[n], acc[1][n], 0, 0, 0); \
            acc[2][n] = __builtin_amdgcn_mfma_f32_16x16x32_bf16(a2, BCUR[n], acc[2][n], 0, 0, 0); \
            acc[3][n] = __builtin_amdgcn_mfma_f32_16x16x32_bf16(a3, BCUR[n], acc[3][n], 0, 0, 0); \
        }                                                                     \
    }

    LOADB(B0, 0);
#pragma unroll
    for (int kk = 0; kk < 8; ++kk) {
        STEP(kk * 2,     B0, B1, offE);
        STEP(kk * 2 + 1, B1, B0, offO);
    }
#undef STEP
#undef LOADB
#undef BOFF

    // ---- pointwise LSTM: lane holds all 4 gates for (row, col) pairs ----
    const int colb = wave * 32 + lr;
#pragma unroll
    for (int j = 0; j < 2; ++j) {
        int col = colb + j * 16;
        float bi = bcat[col], bf_ = bcat[256 + col], bg = bcat[512 + col], bo = bcat[768 + col];
#pragma unroll
        for (int m = 0; m < 4; ++m) {
#pragma unroll
            for (int r = 0; r < 4; ++r) {
                int row = row0 + m * 16 + lk * 4 + r;
                float gi = acc[m][0 * 2 + j][r] + bi;
                float gf = acc[m][1 * 2 + j][r] + bf_;
                float gg = acc[m][2 * 2 + j][r] + bg;
                float go = acc[m][3 * 2 + j][r] + bo;
                float iv = sigm_(gi), fv = sigm_(gf), gv = tanh_(gg), ov = sigm_(go);
                float co = cin[(size_t)row * 256 + col];
                float cn = fv * co + iv * gv;
                float hn = ov * tanh_(cn);
                cout[(size_t)row * 256 + col] = cn;
                hout[(size_t)row * 256 + col] = hn;
            }
        }
    }
}

// ---------------- k_expert: per-(expert, 64-row chunk) routed MLPs ----------------
__global__ __launch_bounds__(256) void k_expert(
    const float* __restrict__ Wa2, const float* __restrict__ ba2,
    const float* __restrict__ Wc2, const float* __restrict__ bc2,
    char* __restrict__ ws, const float* __restrict__ hsrc,
    float* __restrict__ lout, float* __restrict__ vout) {
    const int e = blockIdx.y;
    const int* cur = (const int*)(ws + OFF_CUR);
    int cnt = cur[e] - e * 65536;
    int r0 = blockIdx.x * 64;
    if (r0 >= cnt) return;
    int nr = min(64, cnt - r0);
    const int* permE = (const int*)(ws + OFF_PERM) + (size_t)e * 65536 + r0;

    __shared__ int rows_s[64];
    __shared__ alignas(16) char smem[128 * 66 * 4];
    bf16*  Alds = (bf16*)smem;                        // [32 kc][64 row][8]
    float* haF  = (float*)smem;                       // [128 col][66]

    int t = threadIdx.x;
    if (t < 64) rows_s[t] = permE[(t < nr) ? t : 0];
    __syncthreads();

    { // gather h rows -> bf16 k-packed LDS
        int rowi = t >> 2, q = t & 3;
        const float* hp = hsrc + (size_t)rows_s[rowi] * 256;
#pragma unroll
        for (int s = 0; s < 8; ++s) {
            int kc = s * 4 + q;
            float4 v0 = *(const float4*)(hp + kc * 8);
            float4 v1 = *(const float4*)(hp + kc * 8 + 4);
            bf16x8 o;
            o[0] = (bf16)v0.x; o[1] = (bf16)v0.y; o[2] = (bf16)v0.z; o[3] = (bf16)v0.w;
            o[4] = (bf16)v1.x; o[5] = (bf16)v1.y; o[6] = (bf16)v1.z; o[7] = (bf16)v1.w;
            *(bf16x8*)(Alds + ((size_t)kc * 64 + rowi) * 8) = o;
        }
    }
    __syncthreads();

    const bf16* PW1 = (const bf16*)(ws + OFF_PW1) + (size_t)e * 32 * 128 * 8;
    const float* b1 = (const float*)(ws + OFF_B1) + e * 128;
    int wave = t >> 6, lane = t & 63, lr = lane & 15, lk = lane >> 4;

    f32x4 acc[4][2];
#pragma unroll
    for (int m = 0; m < 4; ++m)
#pragma unroll
        for (int n = 0; n < 2; ++n)
#pragma unroll
            for (int r = 0; r < 4; ++r) acc[m][n][r] = 0.f;

#pragma unroll
    for (int kf = 0; kf < 8; ++kf) {
        bf16x8 a[4], bb[2];
#pragma unroll
        for (int m = 0; m < 4; ++m)
            a[m] = *(const bf16x8*)(Alds + (((kf * 4 + lk) * 64) + (m * 16 + lr)) * 8);
#pragma unroll
        for (int n = 0; n < 2; ++n) {
            int colh = wave * 32 + n * 16 + lr;
            int kc = kf * 4 + lk;
            bb[n] = *(const bf16x8*)(PW1 + ((size_t)kc * 128 + colh) * 8);
        }
#pragma unroll
        for (int m = 0; m < 4; ++m)
#pragma unroll
            for (int n = 0; n < 2; ++n)
                acc[m][n] = __builtin_amdgcn_mfma_f32_16x16x32_bf16(a[m], bb[n], acc[m][n], 0, 0, 0);
    }
    __syncthreads();

#pragma unroll
    for (int m = 0; m < 4; ++m)
#pragma unroll
        for (int n = 0; n < 2; ++n) {
            int colh = wave * 32 + n * 16 + lr;
            float bbv = b1[colh];
#pragma unroll
            for (int r = 0; r < 4; ++r) {
                int row = m * 16 + lk * 4 + r;
                haF[colh * 66 + row] = tanh_(acc[m][n][r] + bbv);
            }
        }
    __syncthreads();

    int row = t & 63;
    int grow = rows_s[row];
    bool valid = row < nr;
#pragma unroll
    for (int p = 0; p < 5; ++p) {
        int aI = p * 4 + (t >> 6);
        if (aI < NA) {
            float s = ba2[e * NA + aI];
            for (int hh = 0; hh < 64; ++hh)
                s += haF[hh * 66 + row] * Wa2[((size_t)e * 64 + hh) * NA + aI];
            if (valid) lout[(size_t)grow * NA + aI] = s;
        }
    }
    if (t < 64) {
        float s = bc2[e];
        for (int hh = 0; hh < 64; ++hh)
            s += haF[(64 + hh) * 66 + row] * Wc2[e * 64 + hh];
        if (valid) vout[grow] = s;
    }
}

extern "C" void kernel_launch(void* const* d_in, const int* in_sizes, int n_in,
                              void* d_out, int out_size, void* d_ws, size_t ws_size,
                              hipStream_t stream) {
    const float* obs  = (const float*)d_in[0];
    const float* h    = (const float*)d_in[1];
    const float* c    = (const float*)d_in[2];
    const int*   idxs = (const int*)d_in[3];
    const float* W_ih = (const float*)d_in[4];
    const float* W_hh = (const float*)d_in[5];
    const float* b_ih = (const float*)d_in[6];
    const float* b_hh = (const float*)d_in[7];
    const float* Wa1  = (const float*)d_in[8];
    const float* ba1  = (const float*)d_in[9];
    const float* Wa2  = (const float*)d_in[10];
    const float* ba2  = (const float*)d_in[11];
    const float* Wc1  = (const float*)d_in[12];
    const float* bc1  = (const float*)d_in[13];
    const float* Wc2  = (const float*)d_in[14];
    const float* bc2  = (const float*)d_in[15];

    float* out  = (float*)d_out;
    float* hout = out;
    float* cout = out + (size_t)NB * ND;
    float* lout = out + (size_t)2 * NB * ND;
    float* vout = lout + (size_t)NB * NA;
    char* ws = (char*)d_ws;

    k_prep1<<<dim3(256), dim3(256), 0, stream>>>(W_ih, W_hh, b_ih, b_hh, ws);
    k_prep2<<<dim3(256), dim3(256), 0, stream>>>(Wa1, Wc1, ba1, bc1, ws);
    k_scatter<<<dim3(256), dim3(256), 0, stream>>>(idxs, ws);
    k_lstm<<<dim3(1024), dim3(512), 0, stream>>>(
        obs, h, c, (const float*)(ws + OFF_BCAT), (const bf16*)(ws + OFF_WCAT), hout, cout);
    k_expert<<<dim3(1024, 16), dim3(256), 0, stream>>>(
        Wa2, ba2, Wc2, bc2, ws, hout, lout, vout);
}

// Round 5
// 222.802 us; speedup vs baseline: 1.2862x; 1.2862x over previous
//
#include <hip/hip_runtime.h>
#include <hip/hip_bf16.h>
#include <math.h>

// Problem constants
#define NB 65536
#define ND 256
#define NE 16
#define NH 64
#define NA 18

typedef __bf16 bf16;
typedef __bf16 bf16x4 __attribute__((ext_vector_type(4)));
typedef __bf16 bf16x8 __attribute__((ext_vector_type(8)));
typedef float  f32x4  __attribute__((ext_vector_type(4)));

// ---- workspace layout (bytes) ----
// Wcat packed bf16, DMA-order [8 kstep][4 cb][2048 units][16B] : 1 MB
#define OFF_WCAT 0u
#define OFF_BCAT 1048576u
#define OFF_PW1  1052672u
#define OFF_B1   2101248u
#define OFF_CUR  2109440u
#define OFF_PERM 2109504u

__device__ __forceinline__ float rcp_(float x) { return __builtin_amdgcn_rcpf(x); }
__device__ __forceinline__ float sigm_(float x) { return rcp_(1.f + __expf(-x)); }
__device__ __forceinline__ float tanh_(float x) {
    float cl = fminf(fmaxf(x, -15.f), 15.f);
    float e = __expf(2.f * cl);
    return (e - 1.f) * rcp_(e + 1.f);
}

__device__ __forceinline__ void gl2lds16(const void* g, void* l) {
    __builtin_amdgcn_global_load_lds(
        (const __attribute__((address_space(1))) unsigned int*)g,
        (__attribute__((address_space(3))) unsigned int*)l, 16, 0, 0);
}

// ---------------- prep1: pack LSTM weights into DMA/frag order ----------------
// unit u within (kstep, cb): u = ((kf*4+g)*256 + colw*4 + lk); holds
// W[col = g*256+cb*64+colw][k = kstep*64+(kf*4+lk)*8 .. +8] as bf16x8.
// Then a K-step stage is ONE contiguous 32KB copy, and the MFMA B-frag read
// (lanes = colw*4+lk) is a perfectly linear 1KB ds_read_b128 sweep.
__global__ void k_prep1(const float* __restrict__ W_ih, const float* __restrict__ W_hh,
                        const float* __restrict__ b_ih, const float* __restrict__ b_hh,
                        char* __restrict__ ws) {
    int t = blockIdx.x * 256 + threadIdx.x;        // 65536 units
    int kstep = t >> 13, rem = t & 8191;
    int cb = rem >> 11, u = rem & 2047;
    int hi = u >> 8, lo = u & 255;
    int kf = hi >> 2, g = hi & 3;
    int colw = lo >> 2, lk = lo & 3;
    int col = g * 256 + cb * 64 + colw;
    int k0 = kstep * 64 + (kf * 4 + lk) * 8;
    const float* src = (k0 < 256) ? (W_ih + (size_t)col * 256 + k0)
                                  : (W_hh + (size_t)col * 256 + (k0 - 256));
    float4 v0 = *(const float4*)(src);
    float4 v1 = *(const float4*)(src + 4);
    bf16x8 o;
    o[0] = (bf16)v0.x; o[1] = (bf16)v0.y; o[2] = (bf16)v0.z; o[3] = (bf16)v0.w;
    o[4] = (bf16)v1.x; o[5] = (bf16)v1.y; o[6] = (bf16)v1.z; o[7] = (bf16)v1.w;
    *(bf16x8*)((bf16*)(ws + OFF_WCAT) + (size_t)t * 8) = o;
    if (t < 1024) ((float*)(ws + OFF_BCAT))[t] = b_ih[t] + b_hh[t];
    if (t < 16)   ((int*)(ws + OFF_CUR))[t] = t * 65536;
}

// ---------------- prep2: pack expert layer-1 weights (actor|critic), fuse biases ----------------
__global__ void k_prep2(const float* __restrict__ Wa1, const float* __restrict__ Wc1,
                        const float* __restrict__ ba1, const float* __restrict__ bc1,
                        char* __restrict__ ws) {
    int t = blockIdx.x * 256 + threadIdx.x;        // 65536 = 16 e * 32 kc * 128 col
    bf16* PW1 = (bf16*)(ws + OFF_PW1);
    int col = t & 127, kc = (t >> 7) & 31, e = t >> 12;
    bf16x8 o;
#pragma unroll
    for (int j = 0; j < 8; ++j) {
        int k = kc * 8 + j;
        float v = (col < 64) ? Wa1[((size_t)e * 256 + k) * 64 + col]
                             : Wc1[((size_t)e * 256 + k) * 64 + (col - 64)];
        o[j] = (bf16)v;
    }
    *(bf16x8*)(PW1 + (((size_t)e * 32 + kc) * 128 + col) * 8) = o;
    if (t < 2048) {
        int e2 = t >> 7, c = t & 127;
        ((float*)(ws + OFF_B1))[t] = (c < 64) ? ba1[e2 * 64 + c] : bc1[e2 * 64 + (c - 64)];
    }
}

// ---------------- scatter: bucket rows by expert ----------------
__global__ void k_scatter(const int* __restrict__ idxs, char* __restrict__ ws) {
    __shared__ int lh[16], lbase[16];
    int t = threadIdx.x;
    int i = blockIdx.x * 256 + t;
    if (t < 16) lh[t] = 0;
    __syncthreads();
    int e = idxs[i];
    int r = atomicAdd(&lh[e], 1);
    __syncthreads();
    int* cur = (int*)(ws + OFF_CUR);
    if (t < 16) lbase[t] = atomicAdd(&cur[t], lh[t]);
    __syncthreads();
    ((int*)(ws + OFF_PERM))[lbase[e] + r] = i;
}

// ---------------- k_lstm v5: m97-style 2-phase pipeline ----------------
// 256 thr (4 waves); tile = 64 rows x 64 c-cols (x4 gates), BK=64, 8 K-steps.
// B via global_load_lds DMA (32KB/step, linear, conflict-free frag reads);
// A reg-staged fp32->bf16 (XOR-swizzled, measured 0-conflict pattern).
// One barrier per K-step; LDS 80KB -> 2 blocks/CU staggered.
__global__ __launch_bounds__(256, 2) void k_lstm(
    const float* __restrict__ obs, const float* __restrict__ hin,
    const float* __restrict__ cin, const float* __restrict__ bcat,
    const char* __restrict__ wcat,
    float* __restrict__ hout, float* __restrict__ cout) {
    __shared__ alignas(16) char Abuf[2][8192];    // [kc 8][row 64][16B], XOR-swizzled
    __shared__ alignas(16) char Bbuf[2][32768];   // linear DMA image, frag-ordered
    const int tid  = threadIdx.x;
    const int w = tid >> 6, lane = tid & 63;
    const int lr = lane & 15, lk = lane >> 4;
    const int rb = blockIdx.x & 1023, cb = blockIdx.x >> 10;
    const int row0 = rb * 64;
    const int colc = cb * 64 + w * 16 + lr;
    const int srw = tid >> 3, sj = tid & 7;       // A-stager: rows srw, srw+32; kc=sj

    const char* WcatBlk = wcat + (size_t)cb * 32768;   // + kstep*131072
    const float* baseO0 = obs + (size_t)(row0 + srw) * 256 + sj * 8;
    const float* baseH0 = hin + (size_t)(row0 + srw) * 256 + sj * 8;

    // A-frag read offsets (kc = kf*4+lk); XOR swizzle matches writer
    int offE[4], offO[4];
#pragma unroll
    for (int m = 0; m < 4; ++m) {
        int R = m * 16 + lr;
        offE[m] = lk * 1024 + ((R ^ lk) * 16);
        offO[m] = (lk + 4) * 1024 + ((R ^ (lk + 4)) * 16);
    }
    // B-frag per-lane base: frag (kf,g) at  kf*16384 + g*4096 + bBase
    const int bBase = (w * 16 + lr) * 64 + lk * 16;

    f32x4 acc[4][4];
#pragma unroll
    for (int m = 0; m < 4; ++m)
#pragma unroll
        for (int g = 0; g < 4; ++g)
#pragma unroll
            for (int r = 0; r < 4; ++r) acc[m][g][r] = 0.f;

#define STAGE_B(bi, ks)                                                      \
    {                                                                        \
        const char* srcB_ = WcatBlk + (size_t)(ks) * 131072;                 \
        _Pragma("unroll")                                                    \
        for (int i_ = 0; i_ < 8; ++i_) {                                     \
            int so_ = (w * 8 + i_) * 1024;                                   \
            gl2lds16(srcB_ + so_ + lane * 16, &Bbuf[bi][so_]);               \
        }                                                                    \
    }
#define LOAD_A(ks)                                                           \
    {                                                                        \
        const float* s0_ = ((ks) < 4) ? (baseO0 + (ks) * 64)                 \
                                      : (baseH0 + ((ks) - 4) * 64);          \
        na0 = *(const float4*)(s0_);                                         \
        na1 = *(const float4*)(s0_ + 4);                                     \
        nb0 = *(const float4*)(s0_ + 32 * 256);                              \
        nb1 = *(const float4*)(s0_ + 32 * 256 + 4);                          \
    }
#define WRITE_A(bi)                                                          \
    {                                                                        \
        bf16x8 oa_, ob_;                                                     \
        oa_[0] = (bf16)na0.x; oa_[1] = (bf16)na0.y; oa_[2] = (bf16)na0.z;    \
        oa_[3] = (bf16)na0.w; oa_[4] = (bf16)na1.x; oa_[5] = (bf16)na1.y;    \
        oa_[6] = (bf16)na1.z; oa_[7] = (bf16)na1.w;                          \
        ob_[0] = (bf16)nb0.x; ob_[1] = (bf16)nb0.y; ob_[2] = (bf16)nb0.z;    \
        ob_[3] = (bf16)nb0.w; ob_[4] = (bf16)nb1.x; ob_[5] = (bf16)nb1.y;    \
        ob_[6] = (bf16)nb1.z; ob_[7] = (bf16)nb1.w;                          \
        *(bf16x8*)(&Abuf[bi][sj * 1024 + ((srw ^ sj) * 16)]) = oa_;          \
        *(bf16x8*)(&Abuf[bi][sj * 1024 + (((srw + 32) ^ sj) * 16)]) = ob_;   \
    }

    // ---- prologue: stage tile 0 ----
    {
        float4 na0, na1, nb0, nb1;
        STAGE_B(0, 0);
        LOAD_A(0);
        WRITE_A(0);
    }
    __syncthreads();

    float cpre[16];

#pragma unroll
    for (int t = 0; t < 8; ++t) {
        const int cur = t & 1;
        float4 na0, na1, nb0, nb1;
        if (t < 7) {
            STAGE_B(cur ^ 1, t + 1);
            LOAD_A(t + 1);
        } else {
            // prefetch cin for the epilogue under the last compute
#pragma unroll
            for (int m = 0; m < 4; ++m)
#pragma unroll
                for (int r = 0; r < 4; ++r)
                    cpre[m * 4 + r] = cin[(size_t)(row0 + m * 16 + lk * 4 + r) * 256 + colc];
        }
        // ---- compute from buffers [cur] ----
#pragma unroll
        for (int kf = 0; kf < 2; ++kf) {
            const char* Ab = Abuf[cur];
            const int* offA = kf ? offO : offE;
            bf16x8 a0 = *(const bf16x8*)(Ab + offA[0]);
            bf16x8 a1 = *(const bf16x8*)(Ab + offA[1]);
            bf16x8 a2 = *(const bf16x8*)(Ab + offA[2]);
            bf16x8 a3 = *(const bf16x8*)(Ab + offA[3]);
            const char* Bb = Bbuf[cur] + kf * 16384 + bBase;
            bf16x8 b0 = *(const bf16x8*)(Bb);
            bf16x8 b1 = *(const bf16x8*)(Bb + 4096);
            bf16x8 b2 = *(const bf16x8*)(Bb + 8192);
            bf16x8 b3 = *(const bf16x8*)(Bb + 12288);
            acc[0][0] = __builtin_amdgcn_mfma_f32_16x16x32_bf16(a0, b0, acc[0][0], 0, 0, 0);
            acc[1][0] = __builtin_amdgcn_mfma_f32_16x16x32_bf16(a1, b0, acc[1][0], 0, 0, 0);
            acc[2][0] = __builtin_amdgcn_mfma_f32_16x16x32_bf16(a2, b0, acc[2][0], 0, 0, 0);
            acc[3][0] = __builtin_amdgcn_mfma_f32_16x16x32_bf16(a3, b0, acc[3][0], 0, 0, 0);
            acc[0][1] = __builtin_amdgcn_mfma_f32_16x16x32_bf16(a0, b1, acc[0][1], 0, 0, 0);
            acc[1][1] = __builtin_amdgcn_mfma_f32_16x16x32_bf16(a1, b1, acc[1][1], 0, 0, 0);
            acc[2][1] = __builtin_amdgcn_mfma_f32_16x16x32_bf16(a2, b1, acc[2][1], 0, 0, 0);
            acc[3][1] = __builtin_amdgcn_mfma_f32_16x16x32_bf16(a3, b1, acc[3][1], 0, 0, 0);
            acc[0][2] = __builtin_amdgcn_mfma_f32_16x16x32_bf16(a0, b2, acc[0][2], 0, 0, 0);
            acc[1][2] = __builtin_amdgcn_mfma_f32_16x16x32_bf16(a1, b2, acc[1][2], 0, 0, 0);
            acc[2][2] = __builtin_amdgcn_mfma_f32_16x16x32_bf16(a2, b2, acc[2][2], 0, 0, 0);
            acc[3][2] = __builtin_amdgcn_mfma_f32_16x16x32_bf16(a3, b2, acc[3][2], 0, 0, 0);
            acc[0][3] = __builtin_amdgcn_mfma_f32_16x16x32_bf16(a0, b3, acc[0][3], 0, 0, 0);
            acc[1][3] = __builtin_amdgcn_mfma_f32_16x16x32_bf16(a1, b3, acc[1][3], 0, 0, 0);
            acc[2][3] = __builtin_amdgcn_mfma_f32_16x16x32_bf16(a2, b3, acc[2][3], 0, 0, 0);
            acc[3][3] = __builtin_amdgcn_mfma_f32_16x16x32_bf16(a3, b3, acc[3][3], 0, 0, 0);
        }
        if (t < 7) WRITE_A(cur ^ 1);
        __syncthreads();
    }
#undef STAGE_B
#undef LOAD_A
#undef WRITE_A

    // ---- pointwise LSTM epilogue: lane holds all 4 gates of (row, colc) ----
    float bi = bcat[colc], bf_ = bcat[256 + colc], bg = bcat[512 + colc], bo = bcat[768 + colc];
#pragma unroll
    for (int m = 0; m < 4; ++m) {
#pragma unroll
        for (int r = 0; r < 4; ++r) {
            int row = row0 + m * 16 + lk * 4 + r;
            float gi = acc[m][0][r] + bi;
            float gf = acc[m][1][r] + bf_;
            float gg = acc[m][2][r] + bg;
            float go = acc[m][3][r] + bo;
            float iv = sigm_(gi), fv = sigm_(gf), gv = tanh_(gg), ov = sigm_(go);
            float cn = fv * cpre[m * 4 + r] + iv * gv;
            float hn = ov * tanh_(cn);
            cout[(size_t)row * 256 + colc] = cn;
            hout[(size_t)row * 256 + colc] = hn;
        }
    }
}

// ---------------- k_expert: per-(expert, 64-row chunk) routed MLPs ----------------
__global__ __launch_bounds__(256) void k_expert(
    const float* __restrict__ Wa2, const float* __restrict__ ba2,
    const float* __restrict__ Wc2, const float* __restrict__ bc2,
    char* __restrict__ ws, const float* __restrict__ hsrc,
    float* __restrict__ lout, float* __restrict__ vout) {
    const int e = blockIdx.y;
    const int* cur = (const int*)(ws + OFF_CUR);
    int cnt = cur[e] - e * 65536;
    int r0 = blockIdx.x * 64;
    if (r0 >= cnt) return;
    int nr = min(64, cnt - r0);
    const int* permE = (const int*)(ws + OFF_PERM) + (size_t)e * 65536 + r0;

    __shared__ int rows_s[64];
    __shared__ alignas(16) char smem[128 * 66 * 4];
    bf16*  Alds = (bf16*)smem;                        // [32 kc][64 row][8]
    float* haF  = (float*)smem;                       // [128 col][66]

    int t = threadIdx.x;
    if (t < 64) rows_s[t] = permE[(t < nr) ? t : 0];
    __syncthreads();

    {
        int rowi = t >> 2, q = t & 3;
        const float* hp = hsrc + (size_t)rows_s[rowi] * 256;
#pragma unroll
        for (int s = 0; s < 8; ++s) {
            int kc = s * 4 + q;
            float4 v0 = *(const float4*)(hp + kc * 8);
            float4 v1 = *(const float4*)(hp + kc * 8 + 4);
            bf16x8 o;
            o[0] = (bf16)v0.x; o[1] = (bf16)v0.y; o[2] = (bf16)v0.z; o[3] = (bf16)v0.w;
            o[4] = (bf16)v1.x; o[5] = (bf16)v1.y; o[6] = (bf16)v1.z; o[7] = (bf16)v1.w;
            *(bf16x8*)(Alds + ((size_t)kc * 64 + rowi) * 8) = o;
        }
    }
    __syncthreads();

    const bf16* PW1 = (const bf16*)(ws + OFF_PW1) + (size_t)e * 32 * 128 * 8;
    const float* b1 = (const float*)(ws + OFF_B1) + e * 128;
    int wave = t >> 6, lane = t & 63, lr = lane & 15, lk = lane >> 4;

    f32x4 acc[4][2];
#pragma unroll
    for (int m = 0; m < 4; ++m)
#pragma unroll
        for (int n = 0; n < 2; ++n)
#pragma unroll
            for (int r = 0; r < 4; ++r) acc[m][n][r] = 0.f;

#pragma unroll
    for (int kf = 0; kf < 8; ++kf) {
        bf16x8 a[4], bb[2];
#pragma unroll
        for (int m = 0; m < 4; ++m)
            a[m] = *(const bf16x8*)(Alds + (((kf * 4 + lk) * 64) + (m * 16 + lr)) * 8);
#pragma unroll
        for (int n = 0; n < 2; ++n) {
            int colh = wave * 32 + n * 16 + lr;
            int kc = kf * 4 + lk;
            bb[n] = *(const bf16x8*)(PW1 + ((size_t)kc * 128 + colh) * 8);
        }
#pragma unroll
        for (int m = 0; m < 4; ++m)
#pragma unroll
            for (int n = 0; n < 2; ++n)
                acc[m][n] = __builtin_amdgcn_mfma_f32_16x16x32_bf16(a[m], bb[n], acc[m][n], 0, 0, 0);
    }
    __syncthreads();

#pragma unroll
    for (int m = 0; m < 4; ++m)
#pragma unroll
        for (int n = 0; n < 2; ++n) {
            int colh = wave * 32 + n * 16 + lr;
            float bbv = b1[colh];
#pragma unroll
            for (int r = 0; r < 4; ++r) {
                int row = m * 16 + lk * 4 + r;
                haF[colh * 66 + row] = tanh_(acc[m][n][r] + bbv);
            }
        }
    __syncthreads();

    int row = t & 63;
    int grow = rows_s[row];
    bool valid = row < nr;
#pragma unroll
    for (int p = 0; p < 5; ++p) {
        int aI = p * 4 + (t >> 6);
        if (aI < NA) {
            float s = ba2[e * NA + aI];
            for (int hh = 0; hh < 64; ++hh)
                s += haF[hh * 66 + row] * Wa2[((size_t)e * 64 + hh) * NA + aI];
            if (valid) lout[(size_t)grow * NA + aI] = s;
        }
    }
    if (t < 64) {
        float s = bc2[e];
        for (int hh = 0; hh < 64; ++hh)
            s += haF[(64 + hh) * 66 + row] * Wc2[e * 64 + hh];
        if (valid) vout[grow] = s;
    }
}

extern "C" void kernel_launch(void* const* d_in, const int* in_sizes, int n_in,
                              void* d_out, int out_size, void* d_ws, size_t ws_size,
                              hipStream_t stream) {
    const float* obs  = (const float*)d_in[0];
    const float* h    = (const float*)d_in[1];
    const float* c    = (const float*)d_in[2];
    const int*   idxs = (const int*)d_in[3];
    const float* W_ih = (const float*)d_in[4];
    const float* W_hh = (const float*)d_in[5];
    const float* b_ih = (const float*)d_in[6];
    const float* b_hh = (const float*)d_in[7];
    const float* Wa1  = (const float*)d_in[8];
    const float* ba1  = (const float*)d_in[9];
    const float* Wa2  = (const float*)d_in[10];
    const float* ba2  = (const float*)d_in[11];
    const float* Wc1  = (const float*)d_in[12];
    const float* bc1  = (const float*)d_in[13];
    const float* Wc2  = (const float*)d_in[14];
    const float* bc2  = (const float*)d_in[15];

    float* out  = (float*)d_out;
    float* hout = out;
    float* cout = out + (size_t)NB * ND;
    float* lout = out + (size_t)2 * NB * ND;
    float* vout = lout + (size_t)NB * NA;
    char* ws = (char*)d_ws;

    k_prep1<<<dim3(256), dim3(256), 0, stream>>>(W_ih, W_hh, b_ih, b_hh, ws);
    k_prep2<<<dim3(256), dim3(256), 0, stream>>>(Wa1, Wc1, ba1, bc1, ws);
    k_scatter<<<dim3(256), dim3(256), 0, stream>>>(idxs, ws);
    k_lstm<<<dim3(4096), dim3(256), 0, stream>>>(
        obs, h, c, (const float*)(ws + OFF_BCAT), (const char*)(ws + OFF_WCAT), hout, cout);
    k_expert<<<dim3(1024, 16), dim3(256), 0, stream>>>(
        Wa2, ba2, Wc2, bc2, ws, hout, lout, vout);
}

// Round 6
// 217.322 us; speedup vs baseline: 1.3187x; 1.0252x over previous
//
#include <hip/hip_runtime.h>
#include <hip/hip_bf16.h>
#include <math.h>

// Problem constants
#define NB 65536
#define ND 256
#define NE 16
#define NH 64
#define NA 18

typedef __bf16 bf16;
typedef __bf16 bf16x4 __attribute__((ext_vector_type(4)));
typedef __bf16 bf16x8 __attribute__((ext_vector_type(8)));
typedef float  f32x4  __attribute__((ext_vector_type(4)));

// ---- workspace layout (bytes) ----
// Wcat packed bf16, DMA-order [8 kstep][4 cb][2048 units][16B] : 1 MB
#define OFF_WCAT 0u
#define OFF_BCAT 1048576u
#define OFF_PW1  1052672u
#define OFF_B1   2101248u
#define OFF_CUR  2109440u
#define OFF_PERM 2109504u

__device__ __forceinline__ float rcp_(float x) { return __builtin_amdgcn_rcpf(x); }
__device__ __forceinline__ float sigm_(float x) { return rcp_(1.f + __expf(-x)); }
__device__ __forceinline__ float tanh_(float x) {
    float cl = fminf(fmaxf(x, -15.f), 15.f);
    float e = __expf(2.f * cl);
    return (e - 1.f) * rcp_(e + 1.f);
}

__device__ __forceinline__ void gl2lds16(const void* g, void* l) {
    __builtin_amdgcn_global_load_lds(
        (const __attribute__((address_space(1))) unsigned int*)g,
        (__attribute__((address_space(3))) unsigned int*)l, 16, 0, 0);
}

// ---------------- prep1: pack LSTM weights into DMA/frag order ----------------
// Region (kstep, cb) = 2048 16B units. Unit idx: kf=idx>>10, g=(idx>>8)&3,
// lk=(idx>>6)&3, u=idx&63; holds W[col = g*256+cb*64+(u^lk)][k = kstep*64+(kf*4+lk)*8 ..+8].
// Reader (lane lr,lk; wave w) hits byte kf*16384+g*4096+lk*1024+((w*16+lr)^lk)*16 —
// the measured-0-conflict A-pattern (XOR within a 1KB page, pages by lk).
__global__ void k_prep1(const float* __restrict__ W_ih, const float* __restrict__ W_hh,
                        const float* __restrict__ b_ih, const float* __restrict__ b_hh,
                        char* __restrict__ ws) {
    int t = blockIdx.x * 256 + threadIdx.x;        // 65536 units
    int kstep = t >> 13;
    int cb    = (t >> 11) & 3;
    int idx   = t & 2047;
    int kf = idx >> 10, g = (idx >> 8) & 3, lk = (idx >> 6) & 3, u = idx & 63;
    int col = g * 256 + cb * 64 + (u ^ lk);
    int k0  = kstep * 64 + (kf * 4 + lk) * 8;
    const float* src = (k0 < 256) ? (W_ih + (size_t)col * 256 + k0)
                                  : (W_hh + (size_t)col * 256 + (k0 - 256));
    float4 v0 = *(const float4*)(src);
    float4 v1 = *(const float4*)(src + 4);
    bf16x8 o;
    o[0] = (bf16)v0.x; o[1] = (bf16)v0.y; o[2] = (bf16)v0.z; o[3] = (bf16)v0.w;
    o[4] = (bf16)v1.x; o[5] = (bf16)v1.y; o[6] = (bf16)v1.z; o[7] = (bf16)v1.w;
    *(bf16x8*)((bf16*)(ws + OFF_WCAT) + (size_t)t * 8) = o;
    if (t < 1024) ((float*)(ws + OFF_BCAT))[t] = b_ih[t] + b_hh[t];
    if (t < 16)   ((int*)(ws + OFF_CUR))[t] = t * 65536;
}

// ---------------- prep2: pack expert layer-1 weights (actor|critic), fuse biases ----------------
__global__ void k_prep2(const float* __restrict__ Wa1, const float* __restrict__ Wc1,
                        const float* __restrict__ ba1, const float* __restrict__ bc1,
                        char* __restrict__ ws) {
    int t = blockIdx.x * 256 + threadIdx.x;        // 65536 = 16 e * 32 kc * 128 col
    bf16* PW1 = (bf16*)(ws + OFF_PW1);
    int col = t & 127, kc = (t >> 7) & 31, e = t >> 12;
    bf16x8 o;
#pragma unroll
    for (int j = 0; j < 8; ++j) {
        int k = kc * 8 + j;
        float v = (col < 64) ? Wa1[((size_t)e * 256 + k) * 64 + col]
                             : Wc1[((size_t)e * 256 + k) * 64 + (col - 64)];
        o[j] = (bf16)v;
    }
    *(bf16x8*)(PW1 + (((size_t)e * 32 + kc) * 128 + col) * 8) = o;
    if (t < 2048) {
        int e2 = t >> 7, c = t & 127;
        ((float*)(ws + OFF_B1))[t] = (c < 64) ? ba1[e2 * 64 + c] : bc1[e2 * 64 + (c - 64)];
    }
}

// ---------------- scatter: bucket rows by expert ----------------
__global__ void k_scatter(const int* __restrict__ idxs, char* __restrict__ ws) {
    __shared__ int lh[16], lbase[16];
    int t = threadIdx.x;
    int i = blockIdx.x * 256 + t;
    if (t < 16) lh[t] = 0;
    __syncthreads();
    int e = idxs[i];
    int r = atomicAdd(&lh[e], 1);
    __syncthreads();
    int* cur = (int*)(ws + OFF_CUR);
    if (t < 16) lbase[t] = atomicAdd(&cur[t], lh[t]);
    __syncthreads();
    ((int*)(ws + OFF_PERM))[lbase[e] + r] = i;
}

// ---------------- k_lstm v6: 2-phase pipeline, conflict-free B, 2-ahead A prefetch ----------------
// 256 thr (4 waves); tile = 64 rows x 64 c-cols (x4 gates), BK=64, 8 K-steps.
// bid = rb*4+cb: panel-sharers dispatch-adjacent (L3-shared A).
__global__ __launch_bounds__(256, 2) void k_lstm(
    const float* __restrict__ obs, const float* __restrict__ hin,
    const float* __restrict__ cin, const float* __restrict__ bcat,
    const char* __restrict__ wcat,
    float* __restrict__ hout, float* __restrict__ cout) {
    __shared__ alignas(16) char Abuf[2][8192];    // [kc 8][row 64][16B], XOR-swizzled
    __shared__ alignas(16) char Bbuf[2][32768];   // DMA image, frag-ordered (prep1)
    const int tid  = threadIdx.x;
    const int w = tid >> 6, lane = tid & 63;
    const int lr = lane & 15, lk = lane >> 4;
    const int rb = blockIdx.x >> 2, cb = blockIdx.x & 3;
    const int row0 = rb * 64;
    const int colc = cb * 64 + w * 16 + lr;
    const int srw = tid >> 3, sj = tid & 7;       // A-stager: rows srw, srw+32; kc=sj

    const char* WcatBlk = wcat + (size_t)cb * 32768;   // + kstep*131072
    const float* baseO0 = obs + (size_t)(row0 + srw) * 256 + sj * 8;
    const float* baseH0 = hin + (size_t)(row0 + srw) * 256 + sj * 8;

    // A-frag read offsets (kc = kf*4+lk); XOR swizzle matches writer
    int offE[4], offO[4];
#pragma unroll
    for (int m = 0; m < 4; ++m) {
        int R = m * 16 + lr;
        offE[m] = lk * 1024 + ((R ^ lk) * 16);
        offO[m] = (lk + 4) * 1024 + ((R ^ (lk + 4)) * 16);
    }
    // B-frag per-lane base (prep1 order): frag (kf,g) at kf*16384 + g*4096 + bBase
    const int bBase = lk * 1024 + (((w * 16 + lr) ^ lk) * 16);

    f32x4 acc[4][4];
#pragma unroll
    for (int m = 0; m < 4; ++m)
#pragma unroll
        for (int g = 0; g < 4; ++g)
#pragma unroll
            for (int r = 0; r < 4; ++r) acc[m][g][r] = 0.f;

#define STAGE_B(bi, ks)                                                      \
    {                                                                        \
        const char* srcB_ = WcatBlk + (size_t)(ks) * 131072;                 \
        _Pragma("unroll")                                                    \
        for (int i_ = 0; i_ < 8; ++i_) {                                     \
            int so_ = (w * 8 + i_) * 1024;                                   \
            gl2lds16(srcB_ + so_ + lane * 16, &Bbuf[bi][so_]);               \
        }                                                                    \
    }
#define LOAD_A(ks, d0, d1, d2, d3)                                           \
    {                                                                        \
        const float* s0_ = ((ks) < 4) ? (baseO0 + (ks) * 64)                 \
                                      : (baseH0 + ((ks) - 4) * 64);          \
        d0 = *(const float4*)(s0_);                                          \
        d1 = *(const float4*)(s0_ + 4);                                      \
        d2 = *(const float4*)(s0_ + 32 * 256);                               \
        d3 = *(const float4*)(s0_ + 32 * 256 + 4);                           \
    }
#define WRITE_A(bi, d0, d1, d2, d3)                                          \
    {                                                                        \
        bf16x8 oa_, ob_;                                                     \
        oa_[0] = (bf16)d0.x; oa_[1] = (bf16)d0.y; oa_[2] = (bf16)d0.z;       \
        oa_[3] = (bf16)d0.w; oa_[4] = (bf16)d1.x; oa_[5] = (bf16)d1.y;       \
        oa_[6] = (bf16)d1.z; oa_[7] = (bf16)d1.w;                            \
        ob_[0] = (bf16)d2.x; ob_[1] = (bf16)d2.y; ob_[2] = (bf16)d2.z;       \
        ob_[3] = (bf16)d2.w; ob_[4] = (bf16)d3.x; ob_[5] = (bf16)d3.y;       \
        ob_[6] = (bf16)d3.z; ob_[7] = (bf16)d3.w;                            \
        *(bf16x8*)(&Abuf[bi][sj * 1024 + ((srw ^ sj) * 16)]) = oa_;          \
        *(bf16x8*)(&Abuf[bi][sj * 1024 + (((srw + 32) ^ sj) * 16)]) = ob_;   \
    }
#define MFMA_STEP(cur)                                                       \
    {                                                                        \
        _Pragma("unroll")                                                    \
        for (int kf = 0; kf < 2; ++kf) {                                     \
            const char* Ab = Abuf[cur];                                      \
            const int* offA = kf ? offO : offE;                              \
            bf16x8 a0 = *(const bf16x8*)(Ab + offA[0]);                      \
            bf16x8 a1 = *(const bf16x8*)(Ab + offA[1]);                      \
            bf16x8 a2 = *(const bf16x8*)(Ab + offA[2]);                      \
            bf16x8 a3 = *(const bf16x8*)(Ab + offA[3]);                      \
            const char* Bb = Bbuf[cur] + kf * 16384 + bBase;                 \
            bf16x8 b0 = *(const bf16x8*)(Bb);                                \
            bf16x8 b1 = *(const bf16x8*)(Bb + 4096);                         \
            bf16x8 b2 = *(const bf16x8*)(Bb + 8192);                         \
            bf16x8 b3 = *(const bf16x8*)(Bb + 12288);                        \
            acc[0][0] = __builtin_amdgcn_mfma_f32_16x16x32_bf16(a0, b0, acc[0][0], 0, 0, 0); \
            acc[1][0] = __builtin_amdgcn_mfma_f32_16x16x32_bf16(a1, b0, acc[1][0], 0, 0, 0); \
            acc[2][0] = __builtin_amdgcn_mfma_f32_16x16x32_bf16(a2, b0, acc[2][0], 0, 0, 0); \
            acc[3][0] = __builtin_amdgcn_mfma_f32_16x16x32_bf16(a3, b0, acc[3][0], 0, 0, 0); \
            acc[0][1] = __builtin_amdgcn_mfma_f32_16x16x32_bf16(a0, b1, acc[0][1], 0, 0, 0); \
            acc[1][1] = __builtin_amdgcn_mfma_f32_16x16x32_bf16(a1, b1, acc[1][1], 0, 0, 0); \
            acc[2][1] = __builtin_amdgcn_mfma_f32_16x16x32_bf16(a2, b1, acc[2][1], 0, 0, 0); \
            acc[3][1] = __builtin_amdgcn_mfma_f32_16x16x32_bf16(a3, b1, acc[3][1], 0, 0, 0); \
            acc[0][2] = __builtin_amdgcn_mfma_f32_16x16x32_bf16(a0, b2, acc[0][2], 0, 0, 0); \
            acc[1][2] = __builtin_amdgcn_mfma_f32_16x16x32_bf16(a1, b2, acc[1][2], 0, 0, 0); \
            acc[2][2] = __builtin_amdgcn_mfma_f32_16x16x32_bf16(a2, b2, acc[2][2], 0, 0, 0); \
            acc[3][2] = __builtin_amdgcn_mfma_f32_16x16x32_bf16(a3, b2, acc[3][2], 0, 0, 0); \
            acc[0][3] = __builtin_amdgcn_mfma_f32_16x16x32_bf16(a0, b3, acc[0][3], 0, 0, 0); \
            acc[1][3] = __builtin_amdgcn_mfma_f32_16x16x32_bf16(a1, b3, acc[1][3], 0, 0, 0); \
            acc[2][3] = __builtin_amdgcn_mfma_f32_16x16x32_bf16(a2, b3, acc[2][3], 0, 0, 0); \
            acc[3][3] = __builtin_amdgcn_mfma_f32_16x16x32_bf16(a3, b3, acc[3][3], 0, 0, 0); \
        }                                                                    \
    }

    float4 pA0, pA1, pA2, pA3;   // prefetch set A
    float4 pB0, pB1, pB2, pB3;   // prefetch set B
    float cpre[16];

    // ---- prologue ----
    LOAD_A(0, pA0, pA1, pA2, pA3);
    STAGE_B(0, 0);
    WRITE_A(0, pA0, pA1, pA2, pA3);          // waits on the A(0) loads
    LOAD_A(1, pA0, pA1, pA2, pA3);           // issue A(1), consumed end of t=0
    __syncthreads();

#pragma unroll
    for (int t = 0; t < 8; ++t) {
        const int cur = t & 1;
        if (t < 7) STAGE_B(cur ^ 1, t + 1);
        if ((t & 1) == 0) {
            if (t + 2 < 8) { LOAD_A(t + 2, pB0, pB1, pB2, pB3); }
        } else {
            if (t + 2 < 8) { LOAD_A(t + 2, pA0, pA1, pA2, pA3); }
        }
        if (t == 6) {
#pragma unroll
            for (int m = 0; m < 4; ++m)
#pragma unroll
                for (int r = 0; r < 4; ++r)
                    cpre[m * 4 + r] = cin[(size_t)(row0 + m * 16 + lk * 4 + r) * 256 + colc];
        }
        MFMA_STEP(cur);
        if (t < 7) {
            if ((t & 1) == 0) { WRITE_A(cur ^ 1, pA0, pA1, pA2, pA3); }
            else              { WRITE_A(cur ^ 1, pB0, pB1, pB2, pB3); }
            __syncthreads();
        }
    }
#undef STAGE_B
#undef LOAD_A
#undef WRITE_A
#undef MFMA_STEP

    // ---- pointwise LSTM epilogue: lane holds all 4 gates of (row, colc) ----
    float bi = bcat[colc], bf_ = bcat[256 + colc], bg = bcat[512 + colc], bo = bcat[768 + colc];
#pragma unroll
    for (int m = 0; m < 4; ++m) {
#pragma unroll
        for (int r = 0; r < 4; ++r) {
            int row = row0 + m * 16 + lk * 4 + r;
            float gi = acc[m][0][r] + bi;
            float gf = acc[m][1][r] + bf_;
            float gg = acc[m][2][r] + bg;
            float go = acc[m][3][r] + bo;
            float iv = sigm_(gi), fv = sigm_(gf), gv = tanh_(gg), ov = sigm_(go);
            float cn = fv * cpre[m * 4 + r] + iv * gv;
            float hn = ov * tanh_(cn);
            cout[(size_t)row * 256 + colc] = cn;
            hout[(size_t)row * 256 + colc] = hn;
        }
    }
}

// ---------------- k_expert: per-(expert, 64-row chunk) routed MLPs ----------------
__global__ __launch_bounds__(256) void k_expert(
    const float* __restrict__ Wa2, const float* __restrict__ ba2,
    const float* __restrict__ Wc2, const float* __restrict__ bc2,
    char* __restrict__ ws, const float* __restrict__ hsrc,
    float* __restrict__ lout, float* __restrict__ vout) {
    const int e = blockIdx.y;
    const int* cur = (const int*)(ws + OFF_CUR);
    int cnt = cur[e] - e * 65536;
    int r0 = blockIdx.x * 64;
    if (r0 >= cnt) return;
    int nr = min(64, cnt - r0);
    const int* permE = (const int*)(ws + OFF_PERM) + (size_t)e * 65536 + r0;

    __shared__ int rows_s[64];
    __shared__ alignas(16) char smem[128 * 66 * 4];
    bf16*  Alds = (bf16*)smem;                        // [32 kc][64 row][8]
    float* haF  = (float*)smem;                       // [128 col][66]

    int t = threadIdx.x;
    if (t < 64) rows_s[t] = permE[(t < nr) ? t : 0];
    __syncthreads();

    {
        int rowi = t >> 2, q = t & 3;
        const float* hp = hsrc + (size_t)rows_s[rowi] * 256;
#pragma unroll
        for (int s = 0; s < 8; ++s) {
            int kc = s * 4 + q;
            float4 v0 = *(const float4*)(hp + kc * 8);
            float4 v1 = *(const float4*)(hp + kc * 8 + 4);
            bf16x8 o;
            o[0] = (bf16)v0.x; o[1] = (bf16)v0.y; o[2] = (bf16)v0.z; o[3] = (bf16)v0.w;
            o[4] = (bf16)v1.x; o[5] = (bf16)v1.y; o[6] = (bf16)v1.z; o[7] = (bf16)v1.w;
            *(bf16x8*)(Alds + ((size_t)kc * 64 + rowi) * 8) = o;
        }
    }
    __syncthreads();

    const bf16* PW1 = (const bf16*)(ws + OFF_PW1) + (size_t)e * 32 * 128 * 8;
    const float* b1 = (const float*)(ws + OFF_B1) + e * 128;
    int wave = t >> 6, lane = t & 63, lr = lane & 15, lk = lane >> 4;

    f32x4 acc[4][2];
#pragma unroll
    for (int m = 0; m < 4; ++m)
#pragma unroll
        for (int n = 0; n < 2; ++n)
#pragma unroll
            for (int r = 0; r < 4; ++r) acc[m][n][r] = 0.f;

#pragma unroll
    for (int kf = 0; kf < 8; ++kf) {
        bf16x8 a[4], bb[2];
#pragma unroll
        for (int m = 0; m < 4; ++m)
            a[m] = *(const bf16x8*)(Alds + (((kf * 4 + lk) * 64) + (m * 16 + lr)) * 8);
#pragma unroll
        for (int n = 0; n < 2; ++n) {
            int colh = wave * 32 + n * 16 + lr;
            int kc = kf * 4 + lk;
            bb[n] = *(const bf16x8*)(PW1 + ((size_t)kc * 128 + colh) * 8);
        }
#pragma unroll
        for (int m = 0; m < 4; ++m)
#pragma unroll
            for (int n = 0; n < 2; ++n)
                acc[m][n] = __builtin_amdgcn_mfma_f32_16x16x32_bf16(a[m], bb[n], acc[m][n], 0, 0, 0);
    }
    __syncthreads();

#pragma unroll
    for (int m = 0; m < 4; ++m)
#pragma unroll
        for (int n = 0; n < 2; ++n) {
            int colh = wave * 32 + n * 16 + lr;
            float bbv = b1[colh];
#pragma unroll
            for (int r = 0; r < 4; ++r) {
                int row = m * 16 + lk * 4 + r;
                haF[colh * 66 + row] = tanh_(acc[m][n][r] + bbv);
            }
        }
    __syncthreads();

    int row = t & 63;
    int grow = rows_s[row];
    bool valid = row < nr;
#pragma unroll
    for (int p = 0; p < 5; ++p) {
        int aI = p * 4 + (t >> 6);
        if (aI < NA) {
            float s = ba2[e * NA + aI];
            for (int hh = 0; hh < 64; ++hh)
                s += haF[hh * 66 + row] * Wa2[((size_t)e * 64 + hh) * NA + aI];
            if (valid) lout[(size_t)grow * NA + aI] = s;
        }
    }
    if (t < 64) {
        float s = bc2[e];
        for (int hh = 0; hh < 64; ++hh)
            s += haF[(64 + hh) * 66 + row] * Wc2[e * 64 + hh];
        if (valid) vout[grow] = s;
    }
}

extern "C" void kernel_launch(void* const* d_in, const int* in_sizes, int n_in,
                              void* d_out, int out_size, void* d_ws, size_t ws_size,
                              hipStream_t stream) {
    const float* obs  = (const float*)d_in[0];
    const float* h    = (const float*)d_in[1];
    const float* c    = (const float*)d_in[2];
    const int*   idxs = (const int*)d_in[3];
    const float* W_ih = (const float*)d_in[4];
    const float* W_hh = (const float*)d_in[5];
    const float* b_ih = (const float*)d_in[6];
    const float* b_hh = (const float*)d_in[7];
    const float* Wa1  = (const float*)d_in[8];
    const float* ba1  = (const float*)d_in[9];
    const float* Wa2  = (const float*)d_in[10];
    const float* ba2  = (const float*)d_in[11];
    const float* Wc1  = (const float*)d_in[12];
    const float* bc1  = (const float*)d_in[13];
    const float* Wc2  = (const float*)d_in[14];
    const float* bc2  = (const float*)d_in[15];

    float* out  = (float*)d_out;
    float* hout = out;
    float* cout = out + (size_t)NB * ND;
    float* lout = out + (size_t)2 * NB * ND;
    float* vout = lout + (size_t)NB * NA;
    char* ws = (char*)d_ws;

    k_prep1<<<dim3(256), dim3(256), 0, stream>>>(W_ih, W_hh, b_ih, b_hh, ws);
    k_prep2<<<dim3(256), dim3(256), 0, stream>>>(Wa1, Wc1, ba1, bc1, ws);
    k_scatter<<<dim3(256), dim3(256), 0, stream>>>(idxs, ws);
    k_lstm<<<dim3(4096), dim3(256), 0, stream>>>(
        obs, h, c, (const float*)(ws + OFF_BCAT), (const char*)(ws + OFF_WCAT), hout, cout);
    k_expert<<<dim3(1024, 16), dim3(256), 0, stream>>>(
        Wa2, ba2, Wc2, bc2, ws, hout, lout, vout);
}

// Round 7
// 199.852 us; speedup vs baseline: 1.4339x; 1.0874x over previous
//
#include <hip/hip_runtime.h>
#include <hip/hip_bf16.h>
#include <math.h>

// Problem constants
#define NB 65536
#define ND 256
#define NE 16
#define NH 64
#define NA 18

typedef __bf16 bf16;
typedef __bf16 bf16x4 __attribute__((ext_vector_type(4)));
typedef __bf16 bf16x8 __attribute__((ext_vector_type(8)));
typedef float  f32x4  __attribute__((ext_vector_type(4)));

// ---- workspace layout (bytes) ----
// Wcat packed bf16, DMA-order [8 kstep][4 cb][2048 units][16B] : 1 MB
#define OFF_WCAT 0u
#define OFF_BCAT 1048576u
#define OFF_PW1  1052672u
#define OFF_B1   2101248u
#define OFF_CUR  2109440u
#define OFF_PERM 2109504u

__device__ __forceinline__ float rcp_(float x) { return __builtin_amdgcn_rcpf(x); }
__device__ __forceinline__ float sigm_(float x) { return rcp_(1.f + __expf(-x)); }
__device__ __forceinline__ float tanh_(float x) {
    float cl = fminf(fmaxf(x, -15.f), 15.f);
    float e = __expf(2.f * cl);
    return (e - 1.f) * rcp_(e + 1.f);
}

__device__ __forceinline__ void gl2lds16(const void* g, void* l) {
    __builtin_amdgcn_global_load_lds(
        (const __attribute__((address_space(1))) unsigned int*)g,
        (__attribute__((address_space(3))) unsigned int*)l, 16, 0, 0);
}

// ---------------- prep1: pack LSTM weights into DMA/frag order ----------------
// Region (kstep, cb) = 2048 16B units. Unit idx: kf=idx>>10, g=(idx>>8)&3,
// lk=(idx>>6)&3, u=idx&63; holds W[col = g*256+cb*64+(u^lk)][k = kstep*64+(kf*4+lk)*8 ..+8].
// Reader (lane lr,lk; wave w) hits byte kf*16384+g*4096+lk*1024+((w*16+lr)^lk)*16 —
// the measured-0-conflict pattern (R6: SQ_LDS_BANK_CONFLICT = 0).
__global__ void k_prep1(const float* __restrict__ W_ih, const float* __restrict__ W_hh,
                        const float* __restrict__ b_ih, const float* __restrict__ b_hh,
                        char* __restrict__ ws) {
    int t = blockIdx.x * 256 + threadIdx.x;        // 65536 units
    int kstep = t >> 13;
    int cb    = (t >> 11) & 3;
    int idx   = t & 2047;
    int kf = idx >> 10, g = (idx >> 8) & 3, lk = (idx >> 6) & 3, u = idx & 63;
    int col = g * 256 + cb * 64 + (u ^ lk);
    int k0  = kstep * 64 + (kf * 4 + lk) * 8;
    const float* src = (k0 < 256) ? (W_ih + (size_t)col * 256 + k0)
                                  : (W_hh + (size_t)col * 256 + (k0 - 256));
    float4 v0 = *(const float4*)(src);
    float4 v1 = *(const float4*)(src + 4);
    bf16x8 o;
    o[0] = (bf16)v0.x; o[1] = (bf16)v0.y; o[2] = (bf16)v0.z; o[3] = (bf16)v0.w;
    o[4] = (bf16)v1.x; o[5] = (bf16)v1.y; o[6] = (bf16)v1.z; o[7] = (bf16)v1.w;
    *(bf16x8*)((bf16*)(ws + OFF_WCAT) + (size_t)t * 8) = o;
    if (t < 1024) ((float*)(ws + OFF_BCAT))[t] = b_ih[t] + b_hh[t];
    if (t < 16)   ((int*)(ws + OFF_CUR))[t] = t * 65536;
}

// ---------------- prep2: pack expert layer-1 weights (actor|critic), fuse biases ----------------
__global__ void k_prep2(const float* __restrict__ Wa1, const float* __restrict__ Wc1,
                        const float* __restrict__ ba1, const float* __restrict__ bc1,
                        char* __restrict__ ws) {
    int t = blockIdx.x * 256 + threadIdx.x;        // 65536 = 16 e * 32 kc * 128 col
    bf16* PW1 = (bf16*)(ws + OFF_PW1);
    int col = t & 127, kc = (t >> 7) & 31, e = t >> 12;
    bf16x8 o;
#pragma unroll
    for (int j = 0; j < 8; ++j) {
        int k = kc * 8 + j;
        float v = (col < 64) ? Wa1[((size_t)e * 256 + k) * 64 + col]
                             : Wc1[((size_t)e * 256 + k) * 64 + (col - 64)];
        o[j] = (bf16)v;
    }
    *(bf16x8*)(PW1 + (((size_t)e * 32 + kc) * 128 + col) * 8) = o;
    if (t < 2048) {
        int e2 = t >> 7, c = t & 127;
        ((float*)(ws + OFF_B1))[t] = (c < 64) ? ba1[e2 * 64 + c] : bc1[e2 * 64 + (c - 64)];
    }
}

// ---------------- scatter: bucket rows by expert ----------------
__global__ void k_scatter(const int* __restrict__ idxs, char* __restrict__ ws) {
    __shared__ int lh[16], lbase[16];
    int t = threadIdx.x;
    int i = blockIdx.x * 256 + t;
    if (t < 16) lh[t] = 0;
    __syncthreads();
    int e = idxs[i];
    int r = atomicAdd(&lh[e], 1);
    __syncthreads();
    int* cur = (int*)(ws + OFF_CUR);
    if (t < 16) lbase[t] = atomicAdd(&cur[t], lh[t]);
    __syncthreads();
    ((int*)(ws + OFF_PERM))[lbase[e] + r] = i;
}

// ---------------- k_lstm v7: single-buffer B (48KB LDS, 3 blocks/CU) + XCD-grouped grid ----------------
// 256 thr (4 waves); tile = 64 rows x 64 c-cols (x4 gates), BK=64, 8 K-steps.
// Per step: ds_read all 8 B-frags -> regs; barrier; gl2lds-stage B(t+1) into the
// SAME buffer + ds_write A(t+1) + issue A(t+2) global loads; 32 MFMA from regs;
// barrier. bid mapping puts the 4 cb-sharers of each A-panel on ONE XCD.
__global__ __launch_bounds__(256, 3) void k_lstm(
    const float* __restrict__ obs, const float* __restrict__ hin,
    const float* __restrict__ cin, const float* __restrict__ bcat,
    const char* __restrict__ wcat,
    float* __restrict__ hout, float* __restrict__ cout) {
    __shared__ alignas(16) char Abuf[2][8192];    // [kc 8][row 64][16B], XOR-swizzled
    __shared__ alignas(16) char Bbuf[32768];      // single buffer, DMA frag-order
    const int tid  = threadIdx.x;
    const int w = tid >> 6, lane = tid & 63;
    const int lr = lane & 15, lk = lane >> 4;
    // XCD-grouped mapping: bid = (rb&7) | ((4*(rb>>3)+cb)<<3)  (bijective)
    const int bid = blockIdx.x;
    const int xcd = bid & 7, rest = bid >> 3;
    const int cb = rest & 3;
    const int rb = ((rest >> 2) << 3) | xcd;
    const int row0 = rb * 64;
    const int colc = cb * 64 + w * 16 + lr;
    const int srw = tid >> 3, sj = tid & 7;       // A-stager: rows srw, srw+32; kc=sj

    const char* WcatBlk = wcat + (size_t)cb * 32768;   // + kstep*131072
    const float* baseO0 = obs + (size_t)(row0 + srw) * 256 + sj * 8;
    const float* baseH0 = hin + (size_t)(row0 + srw) * 256 + sj * 8;

    // A-frag read offsets (kc = kf*4+lk); XOR swizzle matches writer
    int offE[4], offO[4];
#pragma unroll
    for (int m = 0; m < 4; ++m) {
        int R = m * 16 + lr;
        offE[m] = lk * 1024 + ((R ^ lk) * 16);
        offO[m] = (lk + 4) * 1024 + ((R ^ (lk + 4)) * 16);
    }
    // B-frag per-lane base (prep1 order): frag (kf,g) at kf*16384 + g*4096 + bBase
    const int bBase = lk * 1024 + (((w * 16 + lr) ^ lk) * 16);

    f32x4 acc[4][4];
#pragma unroll
    for (int m = 0; m < 4; ++m)
#pragma unroll
        for (int g = 0; g < 4; ++g)
#pragma unroll
            for (int r = 0; r < 4; ++r) acc[m][g][r] = 0.f;

#define STAGE_B(ks)                                                          \
    {                                                                        \
        const char* srcB_ = WcatBlk + (size_t)(ks) * 131072;                 \
        _Pragma("unroll")                                                    \
        for (int i_ = 0; i_ < 8; ++i_) {                                     \
            int so_ = (w * 8 + i_) * 1024;                                   \
            gl2lds16(srcB_ + so_ + lane * 16, &Bbuf[so_]);                   \
        }                                                                    \
    }
#define LOAD_A(ks)                                                           \
    {                                                                        \
        const float* s0_ = ((ks) < 4) ? (baseO0 + (ks) * 64)                 \
                                      : (baseH0 + ((ks) - 4) * 64);          \
        pf0 = *(const float4*)(s0_);                                         \
        pf1 = *(const float4*)(s0_ + 4);                                     \
        pf2 = *(const float4*)(s0_ + 32 * 256);                              \
        pf3 = *(const float4*)(s0_ + 32 * 256 + 4);                          \
    }
#define WRITE_A(bi)                                                          \
    {                                                                        \
        bf16x8 oa_, ob_;                                                     \
        oa_[0] = (bf16)pf0.x; oa_[1] = (bf16)pf0.y; oa_[2] = (bf16)pf0.z;    \
        oa_[3] = (bf16)pf0.w; oa_[4] = (bf16)pf1.x; oa_[5] = (bf16)pf1.y;    \
        oa_[6] = (bf16)pf1.z; oa_[7] = (bf16)pf1.w;                          \
        ob_[0] = (bf16)pf2.x; ob_[1] = (bf16)pf2.y; ob_[2] = (bf16)pf2.z;    \
        ob_[3] = (bf16)pf2.w; ob_[4] = (bf16)pf3.x; ob_[5] = (bf16)pf3.y;    \
        ob_[6] = (bf16)pf3.z; ob_[7] = (bf16)pf3.w;                          \
        *(bf16x8*)(&Abuf[bi][sj * 1024 + ((srw ^ sj) * 16)]) = oa_;          \
        *(bf16x8*)(&Abuf[bi][sj * 1024 + (((srw + 32) ^ sj) * 16)]) = ob_;   \
    }
    // 16 MFMA from A-frags of kc-group (offA) x B-regs (q0..q3)
#define MFMA_HALF(cur, offA, q0, q1, q2, q3)                                 \
    {                                                                        \
        const char* Ab_ = Abuf[cur];                                         \
        bf16x8 a0 = *(const bf16x8*)(Ab_ + offA[0]);                         \
        bf16x8 a1 = *(const bf16x8*)(Ab_ + offA[1]);                         \
        bf16x8 a2 = *(const bf16x8*)(Ab_ + offA[2]);                         \
        bf16x8 a3 = *(const bf16x8*)(Ab_ + offA[3]);                         \
        acc[0][0] = __builtin_amdgcn_mfma_f32_16x16x32_bf16(a0, q0, acc[0][0], 0, 0, 0); \
        acc[1][0] = __builtin_amdgcn_mfma_f32_16x16x32_bf16(a1, q0, acc[1][0], 0, 0, 0); \
        acc[2][0] = __builtin_amdgcn_mfma_f32_16x16x32_bf16(a2, q0, acc[2][0], 0, 0, 0); \
        acc[3][0] = __builtin_amdgcn_mfma_f32_16x16x32_bf16(a3, q0, acc[3][0], 0, 0, 0); \
        acc[0][1] = __builtin_amdgcn_mfma_f32_16x16x32_bf16(a0, q1, acc[0][1], 0, 0, 0); \
        acc[1][1] = __builtin_amdgcn_mfma_f32_16x16x32_bf16(a1, q1, acc[1][1], 0, 0, 0); \
        acc[2][1] = __builtin_amdgcn_mfma_f32_16x16x32_bf16(a2, q1, acc[2][1], 0, 0, 0); \
        acc[3][1] = __builtin_amdgcn_mfma_f32_16x16x32_bf16(a3, q1, acc[3][1], 0, 0, 0); \
        acc[0][2] = __builtin_amdgcn_mfma_f32_16x16x32_bf16(a0, q2, acc[0][2], 0, 0, 0); \
        acc[1][2] = __builtin_amdgcn_mfma_f32_16x16x32_bf16(a1, q2, acc[1][2], 0, 0, 0); \
        acc[2][2] = __builtin_amdgcn_mfma_f32_16x16x32_bf16(a2, q2, acc[2][2], 0, 0, 0); \
        acc[3][2] = __builtin_amdgcn_mfma_f32_16x16x32_bf16(a3, q2, acc[3][2], 0, 0, 0); \
        acc[0][3] = __builtin_amdgcn_mfma_f32_16x16x32_bf16(a0, q3, acc[0][3], 0, 0, 0); \
        acc[1][3] = __builtin_amdgcn_mfma_f32_16x16x32_bf16(a1, q3, acc[1][3], 0, 0, 0); \
        acc[2][3] = __builtin_amdgcn_mfma_f32_16x16x32_bf16(a2, q3, acc[2][3], 0, 0, 0); \
        acc[3][3] = __builtin_amdgcn_mfma_f32_16x16x32_bf16(a3, q3, acc[3][3], 0, 0, 0); \
    }

    float4 pf0, pf1, pf2, pf3;   // A prefetch registers (one 16-KB tile set)
    float cpre[16];

    // ---- prologue: A(0) -> Abuf[0], B(0) -> Bbuf, A(1) -> pref ----
    LOAD_A(0);
    STAGE_B(0);
    WRITE_A(0);            // waits on A(0) loads
    LOAD_A(1);
    __syncthreads();

#pragma unroll
    for (int t = 0; t < 8; ++t) {
        const int cur = t & 1;
        // hoist all 8 B-frags of step t into registers (single-buffer legality)
        const char* Bb0 = Bbuf + bBase;
        bf16x8 br0 = *(const bf16x8*)(Bb0);
        bf16x8 br1 = *(const bf16x8*)(Bb0 + 4096);
        bf16x8 br2 = *(const bf16x8*)(Bb0 + 8192);
        bf16x8 br3 = *(const bf16x8*)(Bb0 + 12288);
        bf16x8 br4 = *(const bf16x8*)(Bb0 + 16384);
        bf16x8 br5 = *(const bf16x8*)(Bb0 + 20480);
        bf16x8 br6 = *(const bf16x8*)(Bb0 + 24576);
        bf16x8 br7 = *(const bf16x8*)(Bb0 + 28672);
        __syncthreads();                      // all B-reads done; buffer reusable
        if (t == 6) {
#pragma unroll
            for (int m = 0; m < 4; ++m)
#pragma unroll
                for (int r = 0; r < 4; ++r)
                    cpre[m * 4 + r] = cin[(size_t)(row0 + m * 16 + lk * 4 + r) * 256 + colc];
        }
        if (t < 7) {
            STAGE_B(t + 1);                   // DMA next B into same buffer
            WRITE_A(cur ^ 1);                 // A(t+1) from pref regs
        }
        if (t < 6) LOAD_A(t + 2);             // refill pref (consumed next step)
        MFMA_HALF(cur, offE, br0, br1, br2, br3);
        MFMA_HALF(cur, offO, br4, br5, br6, br7);
        if (t < 7) __syncthreads();           // B staged + A writes visible
    }
#undef STAGE_B
#undef LOAD_A
#undef WRITE_A
#undef MFMA_HALF

    // ---- pointwise LSTM epilogue: lane holds all 4 gates of (row, colc) ----
    float bi = bcat[colc], bf_ = bcat[256 + colc], bg = bcat[512 + colc], bo = bcat[768 + colc];
#pragma unroll
    for (int m = 0; m < 4; ++m) {
#pragma unroll
        for (int r = 0; r < 4; ++r) {
            int row = row0 + m * 16 + lk * 4 + r;
            float gi = acc[m][0][r] + bi;
            float gf = acc[m][1][r] + bf_;
            float gg = acc[m][2][r] + bg;
            float go = acc[m][3][r] + bo;
            float iv = sigm_(gi), fv = sigm_(gf), gv = tanh_(gg), ov = sigm_(go);
            float cn = fv * cpre[m * 4 + r] + iv * gv;
            float hn = ov * tanh_(cn);
            cout[(size_t)row * 256 + colc] = cn;
            hout[(size_t)row * 256 + colc] = hn;
        }
    }
}

// ---------------- k_expert: per-(expert, 64-row chunk) routed MLPs ----------------
__global__ __launch_bounds__(256) void k_expert(
    const float* __restrict__ Wa2, const float* __restrict__ ba2,
    const float* __restrict__ Wc2, const float* __restrict__ bc2,
    char* __restrict__ ws, const float* __restrict__ hsrc,
    float* __restrict__ lout, float* __restrict__ vout) {
    const int e = blockIdx.y;
    const int* cur = (const int*)(ws + OFF_CUR);
    int cnt = cur[e] - e * 65536;
    int r0 = blockIdx.x * 64;
    if (r0 >= cnt) return;
    int nr = min(64, cnt - r0);
    const int* permE = (const int*)(ws + OFF_PERM) + (size_t)e * 65536 + r0;

    __shared__ int rows_s[64];
    __shared__ alignas(16) char smem[128 * 66 * 4];
    bf16*  Alds = (bf16*)smem;                        // [32 kc][64 row][8]
    float* haF  = (float*)smem;                       // [128 col][66]

    int t = threadIdx.x;
    if (t < 64) rows_s[t] = permE[(t < nr) ? t : 0];
    __syncthreads();

    {
        int rowi = t >> 2, q = t & 3;
        const float* hp = hsrc + (size_t)rows_s[rowi] * 256;
#pragma unroll
        for (int s = 0; s < 8; ++s) {
            int kc = s * 4 + q;
            float4 v0 = *(const float4*)(hp + kc * 8);
            float4 v1 = *(const float4*)(hp + kc * 8 + 4);
            bf16x8 o;
            o[0] = (bf16)v0.x; o[1] = (bf16)v0.y; o[2] = (bf16)v0.z; o[3] = (bf16)v0.w;
            o[4] = (bf16)v1.x; o[5] = (bf16)v1.y; o[6] = (bf16)v1.z; o[7] = (bf16)v1.w;
            *(bf16x8*)(Alds + ((size_t)kc * 64 + rowi) * 8) = o;
        }
    }
    __syncthreads();

    const bf16* PW1 = (const bf16*)(ws + OFF_PW1) + (size_t)e * 32 * 128 * 8;
    const float* b1 = (const float*)(ws + OFF_B1) + e * 128;
    int wave = t >> 6, lane = t & 63, lr = lane & 15, lk = lane >> 4;

    f32x4 acc[4][2];
#pragma unroll
    for (int m = 0; m < 4; ++m)
#pragma unroll
        for (int n = 0; n < 2; ++n)
#pragma unroll
            for (int r = 0; r < 4; ++r) acc[m][n][r] = 0.f;

#pragma unroll
    for (int kf = 0; kf < 8; ++kf) {
        bf16x8 a[4], bb[2];
#pragma unroll
        for (int m = 0; m < 4; ++m)
            a[m] = *(const bf16x8*)(Alds + (((kf * 4 + lk) * 64) + (m * 16 + lr)) * 8);
#pragma unroll
        for (int n = 0; n < 2; ++n) {
            int colh = wave * 32 + n * 16 + lr;
            int kc = kf * 4 + lk;
            bb[n] = *(const bf16x8*)(PW1 + ((size_t)kc * 128 + colh) * 8);
        }
#pragma unroll
        for (int m = 0; m < 4; ++m)
#pragma unroll
            for (int n = 0; n < 2; ++n)
                acc[m][n] = __builtin_amdgcn_mfma_f32_16x16x32_bf16(a[m], bb[n], acc[m][n], 0, 0, 0);
    }
    __syncthreads();

#pragma unroll
    for (int m = 0; m < 4; ++m)
#pragma unroll
        for (int n = 0; n < 2; ++n) {
            int colh = wave * 32 + n * 16 + lr;
            float bbv = b1[colh];
#pragma unroll
            for (int r = 0; r < 4; ++r) {
                int row = m * 16 + lk * 4 + r;
                haF[colh * 66 + row] = tanh_(acc[m][n][r] + bbv);
            }
        }
    __syncthreads();

    int row = t & 63;
    int grow = rows_s[row];
    bool valid = row < nr;
#pragma unroll
    for (int p = 0; p < 5; ++p) {
        int aI = p * 4 + (t >> 6);
        if (aI < NA) {
            float s = ba2[e * NA + aI];
            for (int hh = 0; hh < 64; ++hh)
                s += haF[hh * 66 + row] * Wa2[((size_t)e * 64 + hh) * NA + aI];
            if (valid) lout[(size_t)grow * NA + aI] = s;
        }
    }
    if (t < 64) {
        float s = bc2[e];
        for (int hh = 0; hh < 64; ++hh)
            s += haF[(64 + hh) * 66 + row] * Wc2[e * 64 + hh];
        if (valid) vout[grow] = s;
    }
}

extern "C" void kernel_launch(void* const* d_in, const int* in_sizes, int n_in,
                              void* d_out, int out_size, void* d_ws, size_t ws_size,
                              hipStream_t stream) {
    const float* obs  = (const float*)d_in[0];
    const float* h    = (const float*)d_in[1];
    const float* c    = (const float*)d_in[2];
    const int*   idxs = (const int*)d_in[3];
    const float* W_ih = (const float*)d_in[4];
    const float* W_hh = (const float*)d_in[5];
    const float* b_ih = (const float*)d_in[6];
    const float* b_hh = (const float*)d_in[7];
    const float* Wa1  = (const float*)d_in[8];
    const float* ba1  = (const float*)d_in[9];
    const float* Wa2  = (const float*)d_in[10];
    const float* ba2  = (const float*)d_in[11];
    const float* Wc1  = (const float*)d_in[12];
    const float* bc1  = (const float*)d_in[13];
    const float* Wc2  = (const float*)d_in[14];
    const float* bc2  = (const float*)d_in[15];

    float* out  = (float*)d_out;
    float* hout = out;
    float* cout = out + (size_t)NB * ND;
    float* lout = out + (size_t)2 * NB * ND;
    float* vout = lout + (size_t)NB * NA;
    char* ws = (char*)d_ws;

    k_prep1<<<dim3(256), dim3(256), 0, stream>>>(W_ih, W_hh, b_ih, b_hh, ws);
    k_prep2<<<dim3(256), dim3(256), 0, stream>>>(Wa1, Wc1, ba1, bc1, ws);
    k_scatter<<<dim3(256), dim3(256), 0, stream>>>(idxs, ws);
    k_lstm<<<dim3(4096), dim3(256), 0, stream>>>(
        obs, h, c, (const float*)(ws + OFF_BCAT), (const char*)(ws + OFF_WCAT), hout, cout);
    k_expert<<<dim3(1024, 16), dim3(256), 0, stream>>>(
        Wa2, ba2, Wc2, bc2, ws, hout, lout, vout);
}